// Round 7
// baseline (326.028 us; speedup 1.0000x reference)
//
#include <hip/hip_runtime.h>
#include <hip/hip_bf16.h>
#include <math.h>

#define B_ 4
#define T_ 4096
#define H_ 16
#define D_ 64
#define C_ 1024
#define BT_ (B_*T_)

using short8  = __attribute__((ext_vector_type(8))) short;
using floatx4 = __attribute__((ext_vector_type(4))) float;

__device__ __forceinline__ float feature_map(float x) {
    return x > 0.0f ? x + 1.0f : __expf(x);   // elu(x)+1
}
__device__ __forceinline__ unsigned short f2bf(float x) {
    union { __hip_bfloat16 b; unsigned short u; } c;
    c.b = __float2bfloat16(x);                 // RNE
    return c.u;
}
__device__ __forceinline__ void async16(const void* g, void* l) {
    __builtin_amdgcn_global_load_lds(
        (const __attribute__((address_space(1))) void*)g,
        (__attribute__((address_space(3))) void*)l, 16, 0, 0);
}
__device__ __forceinline__ const char* sel3(const char* a0, const char* a1,
                                            const char* a2, int t) {
    return t == 0 ? a0 : (t == 1 ? a1 : a2);
}

// ---------------------------------------------------------------------------
// K0: fused prep — blocks [0,2048): x fp32->bf16 (grid-stride);
//     blocks [2048,6144): weight transposes (Wqkv then Wout).
// ---------------------------------------------------------------------------
__global__ __launch_bounds__(256)
void prep_kernel(const float4* __restrict__ x, ushort* __restrict__ xb,
                 const float* __restrict__ Wqkv, ushort* __restrict__ WqkvT,
                 const float* __restrict__ Wout, ushort* __restrict__ WoutT)
{
    __shared__ float t[32][33];
    const int bx = blockIdx.x;
    if (bx < 2048) {
        const size_t n = (size_t)BT_ * C_ / 8;
        for (size_t i = (size_t)bx * 256 + threadIdx.x; i < n;
             i += (size_t)2048 * 256) {
            const float4 a = x[2 * i], b = x[2 * i + 1];
            short8 r;
            r[0] = (short)f2bf(a.x); r[1] = (short)f2bf(a.y);
            r[2] = (short)f2bf(a.z); r[3] = (short)f2bf(a.w);
            r[4] = (short)f2bf(b.x); r[5] = (short)f2bf(b.y);
            r[6] = (short)f2bf(b.z); r[7] = (short)f2bf(b.w);
            *reinterpret_cast<short8*>(&xb[i * 8]) = r;
        }
    } else {
        const int id = bx - 2048;                 // 0..4095
        const int xi = id & 127, y = id >> 7;     // 128 x 32
        const bool qkv = xi < 96;
        const float* W  = qkv ? Wqkv : Wout;
        ushort* WT      = qkv ? WqkvT : WoutT;
        const int N     = qkv ? 3 * C_ : C_;
        const int n0 = (qkv ? xi : xi - 96) * 32, k0 = y * 32;
        const int r = threadIdx.x >> 5, c = threadIdx.x & 31;
        #pragma unroll
        for (int i = 0; i < 4; i++)
            t[r + 8 * i][c] = W[(size_t)(k0 + r + 8 * i) * N + n0 + c];
        __syncthreads();
        #pragma unroll
        for (int i = 0; i < 4; i++)
            WT[(size_t)(n0 + r + 8 * i) * C_ + k0 + c] = f2bf(t[c][r + 8 * i]);
    }
}

// ---------------------------------------------------------------------------
// 256x256x(K=1024) bf16 GEMM body, 4 MERGED phases/iteration (r7), B^T
// operands, persistent NTILE chaining. Phase = [BAR; 16 ds_reads; stages;
// lgkm(0); setprio; 32 MFMA; setprio; (VM6 at P34/P78)].
// Stage schedule (re-derived ledger): P12: A1(t+1) | P34: A0,B0,B1(t+2)+VM6
// | P56: A1(t+2) | P78: A0,B0,B1(t+3)+VM6.
//  - overwrite safety: each staged region's last ds_read is in an earlier
//    phase, fenced by that phase's BAR.
//  - VM6 proof: P34's VM6 leaves the t+2 trio in flight -> A1(t+1) landed
//    before P56 reads buf1; P78's VM6 proves {A0,B0,B1}(t+2) + A1(t+2)
//    before next P12/P34 read buf0.
// ---------------------------------------------------------------------------
#define BAR()    __builtin_amdgcn_s_barrier()
#define WAITDS() do { asm volatile("s_waitcnt lgkmcnt(0)" ::: "memory"); \
                      __builtin_amdgcn_sched_barrier(0); } while(0)
#define VM6()    do { asm volatile("s_waitcnt vmcnt(6)" ::: "memory"); \
                      __builtin_amdgcn_sched_barrier(0); } while(0)

#define LDA(slot, mf, ks, buf) \
    aR[slot][ks] = *(const short8*)(smem + (buf)*32768 + ((mf)>>2)*16384 + \
                                    aRowB + ((mf)&3)*2048 + cks##ks)
#define LDB(nf, ks, buf) \
    bR[nf][ks] = *(const short8*)(smem + 65536 + (buf)*32768 + ((nf)>>1)*16384 + \
                                  bRowB + ((nf)&1)*2048 + cks##ks)
#define LDA8(MB, BUF) do { \
    LDA(0, MB+0, 0, BUF); LDA(0, MB+0, 1, BUF); \
    LDA(1, MB+1, 0, BUF); LDA(1, MB+1, 1, BUF); \
    LDA(2, MB+2, 0, BUF); LDA(2, MB+2, 1, BUF); \
    LDA(3, MB+3, 0, BUF); LDA(3, MB+3, 1, BUF); } while(0)
#define LDB4(NF, BUF) do { \
    LDB(NF+0, 0, BUF); LDB(NF+0, 1, BUF); \
    LDB(NF+1, 0, BUF); LDB(NF+1, 1, BUF); } while(0)

#define MM(mf, nf, ks, slot) \
    acc[mf][nf] = __builtin_amdgcn_mfma_f32_16x16x32_bf16( \
        aR[slot][ks], bR[nf][ks], acc[mf][nf], 0, 0, 0)
#define MFMAQ(MB, NF) do { \
    MM(MB+0,NF+0,0,0); MM(MB+1,NF+0,0,1); MM(MB+2,NF+0,0,2); MM(MB+3,NF+0,0,3); \
    MM(MB+0,NF+1,0,0); MM(MB+1,NF+1,0,1); MM(MB+2,NF+1,0,2); MM(MB+3,NF+1,0,3); \
    MM(MB+0,NF+0,1,0); MM(MB+1,NF+0,1,1); MM(MB+2,NF+0,1,2); MM(MB+3,NF+0,1,3); \
    MM(MB+0,NF+1,1,0); MM(MB+1,NF+1,1,1); MM(MB+2,NF+1,1,2); MM(MB+3,NF+1,1,3); \
} while(0)

#define STGA(h, G, buf) do { int _g = (G); if (_g >= NTILE*16) _g -= NTILE*16; \
    const char* _b = sel3(Ab0, Ab1, Ab2, _g >> 4); const int _w = (_g & 15) * 128; \
    async16(_b + aOf##h##0 + _w, smem + (buf)*32768 + (h)*16384 + wv*1024); \
    async16(_b + aOf##h##1 + _w, smem + (buf)*32768 + (h)*16384 + 8192 + wv*1024); \
} while(0)
#define STGB(h, G, buf) do { int _g = (G); if (_g >= NTILE*16) _g -= NTILE*16; \
    const char* _b = sel3(Bb0, Bb1, Bb2, _g >> 4); const int _w = (_g & 15) * 128; \
    async16(_b + bOf##h##0 + _w, smem + 65536 + (buf)*32768 + (h)*16384 + wv*1024); \
    async16(_b + bOf##h##1 + _w, smem + 65536 + (buf)*32768 + (h)*16384 + 8192 + wv*1024); \
} while(0)

#define ITERBODY(GB) \
    const int g1 = (GB) + 2*it + 1, g2 = (GB) + 2*it + 2, g3 = (GB) + 2*it + 3; \
    /* P12 */ BAR(); LDA8(0, 0); LDB4(0, 0); LDB4(2, 0); STGA(1, g1, 1); \
    WAITDS(); __builtin_amdgcn_s_setprio(1); MFMAQ(0, 0); MFMAQ(0, 2); \
    __builtin_amdgcn_s_setprio(0); \
    /* P34 */ BAR(); LDA8(4, 0); STGA(0, g2, 0); STGB(0, g2, 0); STGB(1, g2, 0); \
    WAITDS(); __builtin_amdgcn_s_setprio(1); MFMAQ(4, 2); MFMAQ(4, 0); \
    __builtin_amdgcn_s_setprio(0); VM6(); \
    /* P56 */ BAR(); LDA8(0, 1); LDB4(0, 1); LDB4(2, 1); STGA(1, g2, 0); \
    WAITDS(); __builtin_amdgcn_s_setprio(1); MFMAQ(0, 0); MFMAQ(0, 2); \
    __builtin_amdgcn_s_setprio(0); \
    /* P78 */ BAR(); LDA8(4, 1); STGA(0, g3, 1); STGB(0, g3, 1); STGB(1, g3, 1); \
    WAITDS(); __builtin_amdgcn_s_setprio(1); MFMAQ(4, 2); MFMAQ(4, 0); \
    __builtin_amdgcn_s_setprio(0); VM6();

// register->global epilogue; zeroes acc for next tile
template<int EPI>
__device__ __forceinline__ void gemm_epilogue(
    floatx4 (&acc)[8][4], const float (&bv)[4],
    int mBase, int nBase, int wm, int wn, int lr, int quad,
    ushort* __restrict__ q_out, ushort* __restrict__ kT_out,
    ushort* __restrict__ vT_out, float* __restrict__ f_out)
{
    if (EPI == 0) {
        const float inv_scale = 0.35355339059327373f;  // 1/64^0.25
        const int seg = nBase >> 10;                   // 0=q, 1=k, 2=v
        if (seg == 0) {
            // q' = fm(q)/(z+1e-6); wave wn owns one full head's 64 columns,
            // z = 4-frag sum + shfl_xor over lr (lanes 0..15 of each quad-row).
            #pragma unroll
            for (int mf = 0; mf < 8; mf++)
                #pragma unroll
                for (int i = 0; i < 4; i++) {
                    float f0 = feature_map((acc[mf][0][i] + bv[0]) * inv_scale);
                    float f1 = feature_map((acc[mf][1][i] + bv[1]) * inv_scale);
                    float f2 = feature_map((acc[mf][2][i] + bv[2]) * inv_scale);
                    float f3 = feature_map((acc[mf][3][i] + bv[3]) * inv_scale);
                    float z = f0 + f1 + f2 + f3;
                    z += __shfl_xor(z, 1); z += __shfl_xor(z, 2);
                    z += __shfl_xor(z, 4); z += __shfl_xor(z, 8);
                    const float inv = 1.0f / (z + 1e-6f);
                    const int t = mBase + wm * 128 + mf * 16 + quad * 4 + i;
                    const int cbase = nBase + wn * 64 + lr;
                    q_out[(size_t)t * C_ + cbase]      = f2bf(f0 * inv);
                    q_out[(size_t)t * C_ + cbase + 16] = f2bf(f1 * inv);
                    q_out[(size_t)t * C_ + cbase + 32] = f2bf(f2 * inv);
                    q_out[(size_t)t * C_ + cbase + 48] = f2bf(f3 * inv);
                }
        } else {
            ushort* dstT = (seg == 1) ? kT_out : vT_out;
            #pragma unroll
            for (int nf = 0; nf < 4; nf++) {
                const int c = (nBase + wn * 64 + nf * 16 + lr) & 1023;
                #pragma unroll
                for (int mf = 0; mf < 8; mf++) {
                    float v0 = acc[mf][nf][0] + bv[nf], v1 = acc[mf][nf][1] + bv[nf];
                    float v2 = acc[mf][nf][2] + bv[nf], v3 = acc[mf][nf][3] + bv[nf];
                    if (seg == 1) {
                        v0 = feature_map(v0 * inv_scale); v1 = feature_map(v1 * inv_scale);
                        v2 = feature_map(v2 * inv_scale); v3 = feature_map(v3 * inv_scale);
                    }
                    const int tt = mBase + wm * 128 + mf * 16 + quad * 4;
                    *(ushort4*)&dstT[(size_t)c * BT_ + tt] =
                        make_ushort4(f2bf(v0), f2bf(v1), f2bf(v2), f2bf(v3));
                }
            }
        }
    } else {
        #pragma unroll
        for (int nf = 0; nf < 4; nf++) {
            const int c = nBase + wn * 64 + nf * 16 + lr;
            #pragma unroll
            for (int mf = 0; mf < 8; mf++)
                #pragma unroll
                for (int i = 0; i < 4; i++) {
                    const int row = mBase + wm * 128 + mf * 16 + quad * 4 + i;
                    f_out[(size_t)row * C_ + c] = acc[mf][nf][i] + bv[nf];
                }
        }
    }
    #pragma unroll
    for (int i = 0; i < 8; i++)
        #pragma unroll
        for (int j = 0; j < 4; j++) acc[i][j] = (floatx4)0.0f;
}

template<int EPI, int NBX, int NTILE>
__device__ __forceinline__ void gemm_body(
    const ushort* __restrict__ A, const ushort* __restrict__ Bm,
    const float* __restrict__ bias,
    ushort* __restrict__ q_out, ushort* __restrict__ kT_out,
    ushort* __restrict__ vT_out, float* __restrict__ f_out)
{
    __shared__ __align__(16) unsigned char smem[131072];

    const int tid = threadIdx.x;
    const int wv = tid >> 6, l = tid & 63;
    const int wm = wv >> 2, wn = wv & 3;
    const int lr = l & 15, quad = l >> 4;

    int mB0, mB1, mB2, nB0, nB1, nB2;
    {
        const int tot = (int)gridDim.x * NTILE, cpx = tot >> 3;
        int lg0 = blockIdx.x;
        int w0 = (lg0 & 7) * cpx + (lg0 >> 3);
        mB0 = (w0 / NBX) * 256; nB0 = (w0 % NBX) * 256;
        if (NTILE > 1) {
            int lg1 = blockIdx.x + (int)gridDim.x;
            int w1 = (lg1 & 7) * cpx + (lg1 >> 3);
            mB1 = (w1 / NBX) * 256; nB1 = (w1 % NBX) * 256;
            int lg2 = blockIdx.x + 2 * (int)gridDim.x;
            int w2 = (lg2 & 7) * cpx + (lg2 >> 3);
            mB2 = (w2 / NBX) * 256; nB2 = (w2 % NBX) * 256;
        } else { mB1 = mB0; nB1 = nB0; mB2 = mB0; nB2 = nB0; }
    }
    // EPI=1: B panel differs per batch b = mBase>>12 (KWT[b])
    const size_t bOffB = (EPI == 1) ? (size_t)(mB0 >> 12) * ((size_t)C_ * C_) : 0;
    const char* Ab0 = (const char*)(A + (size_t)mB0 * C_);
    const char* Ab1 = (const char*)(A + (size_t)mB1 * C_);
    const char* Ab2 = (const char*)(A + (size_t)mB2 * C_);
    const char* Bb0 = (const char*)(Bm + bOffB + (size_t)nB0 * C_);
    const char* Bb1 = (const char*)(Bm + bOffB + (size_t)nB1 * C_);
    const char* Bb2 = (const char*)(Bm + bOffB + (size_t)nB2 * C_);

    float bv0[4], bv1[4], bv2[4];
    #pragma unroll
    for (int nf = 0; nf < 4; nf++) {
        bv0[nf] = bias[nB0 + wn * 64 + nf * 16 + lr];
        bv1[nf] = (NTILE > 1) ? bias[nB1 + wn * 64 + nf * 16 + lr] : bv0[nf];
        bv2[nf] = (NTILE > 1) ? bias[nB2 + wn * 64 + nf * 16 + lr] : bv0[nf];
    }

    const int s0 = tid >> 3;
    const int cb = ((tid & 7) * 16) ^ ((s0 & 7) << 4);
    const int aOf00 = (s0)       * 2048 + cb;
    const int aOf01 = (128 + s0) * 2048 + cb;
    const int aOf10 = (64 + s0)  * 2048 + cb;
    const int aOf11 = (192 + s0) * 2048 + cb;
    const int bq    = (s0 >> 5) * 64 + (s0 & 31);
    const int bOf00 = (bq)       * 2048 + cb;
    const int bOf01 = (bq + 128) * 2048 + cb;
    const int bOf10 = (bq + 32)  * 2048 + cb;
    const int bOf11 = (bq + 160) * 2048 + cb;

    const int aRowB = (wm * 64 + lr) * 128;
    const int bRowB = (wn * 32 + lr) * 128;
    const int cks0 = (quad * 16) ^ ((lr & 7) << 4);
    const int cks1 = 64 ^ cks0;

    floatx4 acc[8][4];
    #pragma unroll
    for (int i = 0; i < 8; i++)
        #pragma unroll
        for (int j = 0; j < 4; j++) acc[i][j] = (floatx4)0.0f;
    short8 aR[4][2], bR[4][2];

    STGA(0, 0, 0); STGB(0, 0, 0); STGB(1, 0, 0); STGA(1, 0, 0);
    STGA(0, 1, 1); STGB(0, 1, 1); STGB(1, 1, 1);
    asm volatile("s_waitcnt vmcnt(6)" ::: "memory");
    __builtin_amdgcn_sched_barrier(0);

    #pragma unroll 1
    for (int it = 0; it < 8; ++it) { ITERBODY(0) }
    gemm_epilogue<EPI>(acc, bv0, mB0, nB0, wm, wn, lr, quad,
                       q_out, kT_out, vT_out, f_out);
    if (NTILE > 1) {
        #pragma unroll 1
        for (int it = 0; it < 8; ++it) { ITERBODY(16) }
        gemm_epilogue<EPI>(acc, bv1, mB1, nB1, wm, wn, lr, quad,
                           q_out, kT_out, vT_out, f_out);
        #pragma unroll 1
        for (int it = 0; it < 8; ++it) { ITERBODY(32) }
        gemm_epilogue<EPI>(acc, bv2, mB2, nB2, wm, wn, lr, quad,
                           q_out, kT_out, vT_out, f_out);
    }
    asm volatile("s_waitcnt vmcnt(0)" ::: "memory");
}

__global__ __launch_bounds__(512, 2)
void qkv8_kernel(const ushort* __restrict__ A, const ushort* __restrict__ Bm,
                 const float* __restrict__ bias, ushort* __restrict__ q_out,
                 ushort* __restrict__ kT_out, ushort* __restrict__ vT_out)
{
    gemm_body<0, 12, 3>(A, Bm, bias, q_out, kT_out, vT_out, nullptr);
}

__global__ __launch_bounds__(512, 2)
void outproj8_kernel(const ushort* __restrict__ A, const ushort* __restrict__ Bm,
                     const float* __restrict__ bias, float* __restrict__ f_out)
{
    gemm_body<1, 4, 1>(A, Bm, bias, nullptr, nullptr, nullptr, f_out);
}

// ---------------------------------------------------------------------------
// K2: kv[b,h][d][m] += sum_t km[t][d]*v[t][m]. grid (tsplit=8, b*h=64).
// ---------------------------------------------------------------------------
__global__ __launch_bounds__(256)
void kv_accum_kernel(const ushort* __restrict__ kmT, const ushort* __restrict__ vT,
                     float* __restrict__ kv)
{
    const int tid = threadIdx.x;
    const int w = tid >> 6, l = tid & 63;
    const int wm = w >> 1, wn = w & 1;
    const int lr = l & 15, quad = l >> 4;
    const int bh = blockIdx.y;
    const int b = bh >> 4, h = bh & 15;
    const size_t t0 = (size_t)b * T_ + (size_t)blockIdx.x * 512;

    const ushort* Ar = kmT + (size_t)(h * 64 + wm * 32 + lr) * BT_ + t0 + quad * 8;
    const ushort* Br = vT  + (size_t)(h * 64 + wn * 32 + lr) * BT_ + t0 + quad * 8;

    floatx4 acc[2][2];
    #pragma unroll
    for (int i = 0; i < 2; i++)
        #pragma unroll
        for (int j = 0; j < 2; j++) acc[i][j] = (floatx4)0.0f;

    #pragma unroll 8
    for (int tt = 0; tt < 512; tt += 32) {
        const short8 af0 = *(const short8*)&Ar[tt];
        const short8 af1 = *(const short8*)&Ar[(size_t)16 * BT_ + tt];
        const short8 bf0 = *(const short8*)&Br[tt];
        const short8 bf1 = *(const short8*)&Br[(size_t)16 * BT_ + tt];
        acc[0][0] = __builtin_amdgcn_mfma_f32_16x16x32_bf16(af0, bf0, acc[0][0], 0, 0, 0);
        acc[0][1] = __builtin_amdgcn_mfma_f32_16x16x32_bf16(af0, bf1, acc[0][1], 0, 0, 0);
        acc[1][0] = __builtin_amdgcn_mfma_f32_16x16x32_bf16(af1, bf0, acc[1][0], 0, 0, 0);
        acc[1][1] = __builtin_amdgcn_mfma_f32_16x16x32_bf16(af1, bf1, acc[1][1], 0, 0, 0);
    }

    float* kvb = kv + (size_t)bh * (D_ * D_);
    #pragma unroll
    for (int i = 0; i < 2; i++)
        #pragma unroll
        for (int j = 0; j < 2; j++)
            #pragma unroll
            for (int r = 0; r < 4; r++) {
                const int d = wm * 32 + i * 16 + quad * 4 + r;
                const int m = wn * 32 + j * 16 + lr;
                atomicAdd(&kvb[d * 64 + m], acc[i][j][r]);
            }
}

// ---------------------------------------------------------------------------
// K3: KWT[b][c][h*64+d] = sum_m kv[b,h][d][m] * Wout[h*64+m][c]
//     grid (4 cblk, 64 bh); wave w: c-range cblk*256 + w*64; K=64.
// ---------------------------------------------------------------------------
__global__ __launch_bounds__(256)
void kw_kernel(const float* __restrict__ kv, const ushort* __restrict__ WoutT,
               ushort* __restrict__ KWT)
{
    const int tid = threadIdx.x;
    const int w = tid >> 6, l = tid & 63;
    const int lr = l & 15, quad = l >> 4;
    const int bh = blockIdx.y, b = bh >> 4, h = bh & 15;
    const int c0 = blockIdx.x * 256 + w * 64;

    const float* kvb = kv + (size_t)bh * (D_ * D_);

    short8 bf[4][2];
    #pragma unroll
    for (int df = 0; df < 4; df++)
        #pragma unroll
        for (int ks = 0; ks < 2; ks++) {
            const float* src = &kvb[(df * 16 + lr) * 64 + ks * 32 + quad * 8];
            const float4 u0 = *(const float4*)src;
            const float4 u1 = *(const float4*)(src + 4);
            short8 t;
            t[0] = (short)f2bf(u0.x); t[1] = (short)f2bf(u0.y);
            t[2] = (short)f2bf(u0.z); t[3] = (short)f2bf(u0.w);
            t[4] = (short)f2bf(u1.x); t[5] = (short)f2bf(u1.y);
            t[6] = (short)f2bf(u1.z); t[7] = (short)f2bf(u1.w);
            bf[df][ks] = t;
        }

    floatx4 acc[4][4];
    #pragma unroll
    for (int i = 0; i < 4; i++)
        #pragma unroll
        for (int j = 0; j < 4; j++) acc[i][j] = (floatx4)0.0f;

    #pragma unroll
    for (int ks = 0; ks < 2; ks++) {
        short8 af[4];
        #pragma unroll
        for (int cf = 0; cf < 4; cf++)
            af[cf] = *(const short8*)&WoutT[(size_t)(c0 + cf * 16 + lr) * C_
                                            + h * 64 + ks * 32 + quad * 8];
        #pragma unroll
        for (int cf = 0; cf < 4; cf++)
            #pragma unroll
            for (int df = 0; df < 4; df++)
                acc[cf][df] = __builtin_amdgcn_mfma_f32_16x16x32_bf16(
                    af[cf], bf[df][ks], acc[cf][df], 0, 0, 0);
    }

    ushort* dst = KWT + (size_t)b * (C_ * C_);
    #pragma unroll
    for (int cf = 0; cf < 4; cf++)
        #pragma unroll
        for (int i = 0; i < 4; i++) {
            const int c = c0 + cf * 16 + quad * 4 + i;
            #pragma unroll
            for (int df = 0; df < 4; df++)
                dst[(size_t)c * C_ + h * 64 + df * 16 + lr] = f2bf(acc[cf][df][i]);
        }
}

// ---------------------------------------------------------------------------
// Workspace map:
//   ws:    xb 33.5M (-> KWT 8M after QKV) | WqkvT 6.3M | WoutT 2M |
//          qs 33.5M | kv 1M                              (= 76,546,048 B)
//   d_out: kmT 33.5M | vT 33.5M  (both dead before outproj writes out)
// ---------------------------------------------------------------------------
extern "C" void kernel_launch(void* const* d_in, const int* in_sizes, int n_in,
                              void* d_out, int out_size, void* d_ws, size_t ws_size,
                              hipStream_t stream)
{
    const float* x    = (const float*)d_in[0];
    const float* Wqkv = (const float*)d_in[1];
    const float* bqkv = (const float*)d_in[2];
    const float* Wout = (const float*)d_in[3];
    const float* bout = (const float*)d_in[4];
    float* out = (float*)d_out;

    char* ws = (char*)d_ws;
    ushort* xb     = (ushort*)ws;                       // 33,554,432 B
    ushort* WqkvT  = (ushort*)(ws + 33554432);          //  6,291,456 B
    ushort* WoutT  = (ushort*)(ws + 39845888);          //  2,097,152 B
    ushort* qs     = (ushort*)(ws + 41943040);          // 33,554,432 B (q')
    float*  kv     = (float*) (ws + 75497472);          //  1,048,576 B
    ushort* KWT    = (ushort*)ws;                       // alias xb (dead after QKV)
    ushort* kmT    = (ushort*)d_out;                    // scratch in d_out
    ushort* vT     = (ushort*)((char*)d_out + 33554432);

    hipMemsetAsync(kv, 0, (size_t)B_ * H_ * D_ * D_ * sizeof(float), stream);

    prep_kernel<<<6144, 256, 0, stream>>>((const float4*)x, xb,
                                          Wqkv, WqkvT, Wout, WoutT);

    qkv8_kernel<<<dim3(256), 512, 0, stream>>>(xb, WqkvT, bqkv, qs, kmT, vT);
    kv_accum_kernel<<<dim3(8, B_ * H_), 256, 0, stream>>>(kmT, vT, kv);
    kw_kernel<<<dim3(4, B_ * H_), 256, 0, stream>>>(kv, WoutT, KWT);
    outproj8_kernel<<<dim3(256), 512, 0, stream>>>(qs, KWT, bout, out);
}

// Round 8
// 309.604 us; speedup vs baseline: 1.0531x; 1.0531x over previous
//
#include <hip/hip_runtime.h>
#include <hip/hip_bf16.h>
#include <math.h>

#define B_ 4
#define T_ 4096
#define H_ 16
#define D_ 64
#define C_ 1024
#define BT_ (B_*T_)

using short8  = __attribute__((ext_vector_type(8))) short;
using floatx4 = __attribute__((ext_vector_type(4))) float;

__device__ __forceinline__ float feature_map(float x) {
    return x > 0.0f ? x + 1.0f : __expf(x);   // elu(x)+1
}
__device__ __forceinline__ unsigned short f2bf(float x) {
    union { __hip_bfloat16 b; unsigned short u; } c;
    c.b = __float2bfloat16(x);                 // RNE
    return c.u;
}
__device__ __forceinline__ void async16(const void* g, void* l) {
    __builtin_amdgcn_global_load_lds(
        (const __attribute__((address_space(1))) void*)g,
        (__attribute__((address_space(3))) void*)l, 16, 0, 0);
}
__device__ __forceinline__ const char* sel3(const char* a0, const char* a1,
                                            const char* a2, int t) {
    return t == 0 ? a0 : (t == 1 ? a1 : a2);
}

// ---------------------------------------------------------------------------
// K0: fused prep — blocks [0,2048): x fp32->bf16 (grid-stride);
//     blocks [2048,6144): weight transposes (Wqkv then Wout).
// ---------------------------------------------------------------------------
__global__ __launch_bounds__(256)
void prep_kernel(const float4* __restrict__ x, ushort* __restrict__ xb,
                 const float* __restrict__ Wqkv, ushort* __restrict__ WqkvT,
                 const float* __restrict__ Wout, ushort* __restrict__ WoutT)
{
    __shared__ float t[32][33];
    const int bx = blockIdx.x;
    if (bx < 2048) {
        const size_t n = (size_t)BT_ * C_ / 8;
        for (size_t i = (size_t)bx * 256 + threadIdx.x; i < n;
             i += (size_t)2048 * 256) {
            const float4 a = x[2 * i], b = x[2 * i + 1];
            short8 r;
            r[0] = (short)f2bf(a.x); r[1] = (short)f2bf(a.y);
            r[2] = (short)f2bf(a.z); r[3] = (short)f2bf(a.w);
            r[4] = (short)f2bf(b.x); r[5] = (short)f2bf(b.y);
            r[6] = (short)f2bf(b.z); r[7] = (short)f2bf(b.w);
            *reinterpret_cast<short8*>(&xb[i * 8]) = r;
        }
    } else {
        const int id = bx - 2048;                 // 0..4095
        const int xi = id & 127, y = id >> 7;     // 128 x 32
        const bool qkv = xi < 96;
        const float* W  = qkv ? Wqkv : Wout;
        ushort* WT      = qkv ? WqkvT : WoutT;
        const int N     = qkv ? 3 * C_ : C_;
        const int n0 = (qkv ? xi : xi - 96) * 32, k0 = y * 32;
        const int r = threadIdx.x >> 5, c = threadIdx.x & 31;
        #pragma unroll
        for (int i = 0; i < 4; i++)
            t[r + 8 * i][c] = W[(size_t)(k0 + r + 8 * i) * N + n0 + c];
        __syncthreads();
        #pragma unroll
        for (int i = 0; i < 4; i++)
            WT[(size_t)(n0 + r + 8 * i) * C_ + k0 + c] = f2bf(t[c][r + 8 * i]);
    }
}

// ---------------------------------------------------------------------------
// 256x256x(K=1024) bf16 8-phase GEMM body (T1+T2+T3+T4+T5), B^T operands,
// persistent NTILE chaining. SINGLE barrier per phase (validated r6 bench):
// phase = [BAR; ds_reads; stage; lgkm(0); setprio; 16 MFMA; setprio;
// (VM6 at p4/p8)]. Stage order/iter: p1 A1(t+1)|b1, p2 A0(t+2)|b0,
// p3 B0(t+2)|b0, p4 B1(t+2)|b0 +VM6, p5 A1(t+2)|b0, p6 A0(t+3)|b1,
// p7 B0(t+3)|b1, p8 B1(t+3)|b1 +VM6.
// ---------------------------------------------------------------------------
#define BAR()    __builtin_amdgcn_s_barrier()
#define WAITDS() do { asm volatile("s_waitcnt lgkmcnt(0)" ::: "memory"); \
                      __builtin_amdgcn_sched_barrier(0); } while(0)
#define VM6()    do { asm volatile("s_waitcnt vmcnt(6)" ::: "memory"); \
                      __builtin_amdgcn_sched_barrier(0); } while(0)

#define LDA(slot, mf, ks, buf) \
    aR[slot][ks] = *(const short8*)(smem + (buf)*32768 + ((mf)>>2)*16384 + \
                                    aRowB + ((mf)&3)*2048 + cks##ks)
#define LDB(nf, ks, buf) \
    bR[nf][ks] = *(const short8*)(smem + 65536 + (buf)*32768 + ((nf)>>1)*16384 + \
                                  bRowB + ((nf)&1)*2048 + cks##ks)
#define LDA8(MB, BUF) do { \
    LDA(0, MB+0, 0, BUF); LDA(0, MB+0, 1, BUF); \
    LDA(1, MB+1, 0, BUF); LDA(1, MB+1, 1, BUF); \
    LDA(2, MB+2, 0, BUF); LDA(2, MB+2, 1, BUF); \
    LDA(3, MB+3, 0, BUF); LDA(3, MB+3, 1, BUF); } while(0)
#define LDB4(NF, BUF) do { \
    LDB(NF+0, 0, BUF); LDB(NF+0, 1, BUF); \
    LDB(NF+1, 0, BUF); LDB(NF+1, 1, BUF); } while(0)

#define MM(mf, nf, ks, slot) \
    acc[mf][nf] = __builtin_amdgcn_mfma_f32_16x16x32_bf16( \
        aR[slot][ks], bR[nf][ks], acc[mf][nf], 0, 0, 0)
#define MFMAQ(MB, NF) do { \
    MM(MB+0,NF+0,0,0); MM(MB+1,NF+0,0,1); MM(MB+2,NF+0,0,2); MM(MB+3,NF+0,0,3); \
    MM(MB+0,NF+1,0,0); MM(MB+1,NF+1,0,1); MM(MB+2,NF+1,0,2); MM(MB+3,NF+1,0,3); \
    MM(MB+0,NF+0,1,0); MM(MB+1,NF+0,1,1); MM(MB+2,NF+0,1,2); MM(MB+3,NF+0,1,3); \
    MM(MB+0,NF+1,1,0); MM(MB+1,NF+1,1,1); MM(MB+2,NF+1,1,2); MM(MB+3,NF+1,1,3); \
} while(0)

#define STGA(h, G, buf) do { int _g = (G); if (_g >= NTILE*16) _g -= NTILE*16; \
    const char* _b = sel3(Ab0, Ab1, Ab2, _g >> 4); const int _w = (_g & 15) * 128; \
    async16(_b + aOf##h##0 + _w, smem + (buf)*32768 + (h)*16384 + wv*1024); \
    async16(_b + aOf##h##1 + _w, smem + (buf)*32768 + (h)*16384 + 8192 + wv*1024); \
} while(0)
#define STGB(h, G, buf) do { int _g = (G); if (_g >= NTILE*16) _g -= NTILE*16; \
    const char* _b = sel3(Bb0, Bb1, Bb2, _g >> 4); const int _w = (_g & 15) * 128; \
    async16(_b + bOf##h##0 + _w, smem + 65536 + (buf)*32768 + (h)*16384 + wv*1024); \
    async16(_b + bOf##h##1 + _w, smem + 65536 + (buf)*32768 + (h)*16384 + 8192 + wv*1024); \
} while(0)

#define ITERBODY(GB) \
    const int g1 = (GB) + 2*it + 1, g2 = (GB) + 2*it + 2, g3 = (GB) + 2*it + 3; \
    /* p1 */ BAR(); LDA8(0, 0); LDB4(0, 0); STGA(1, g1, 1); \
    WAITDS(); __builtin_amdgcn_s_setprio(1); MFMAQ(0, 0); \
    __builtin_amdgcn_s_setprio(0); \
    /* p2 */ BAR(); LDB4(2, 0); STGA(0, g2, 0); \
    WAITDS(); __builtin_amdgcn_s_setprio(1); MFMAQ(0, 2); \
    __builtin_amdgcn_s_setprio(0); \
    /* p3 */ BAR(); LDA8(4, 0); STGB(0, g2, 0); \
    WAITDS(); __builtin_amdgcn_s_setprio(1); MFMAQ(4, 2); \
    __builtin_amdgcn_s_setprio(0); \
    /* p4 */ BAR(); STGB(1, g2, 0); \
    WAITDS(); __builtin_amdgcn_s_setprio(1); MFMAQ(4, 0); \
    __builtin_amdgcn_s_setprio(0); VM6(); \
    /* p5 */ BAR(); LDA8(0, 1); LDB4(0, 1); STGA(1, g2, 0); \
    WAITDS(); __builtin_amdgcn_s_setprio(1); MFMAQ(0, 0); \
    __builtin_amdgcn_s_setprio(0); \
    /* p6 */ BAR(); LDB4(2, 1); STGA(0, g3, 1); \
    WAITDS(); __builtin_amdgcn_s_setprio(1); MFMAQ(0, 2); \
    __builtin_amdgcn_s_setprio(0); \
    /* p7 */ BAR(); LDA8(4, 1); STGB(0, g3, 1); \
    WAITDS(); __builtin_amdgcn_s_setprio(1); MFMAQ(4, 2); \
    __builtin_amdgcn_s_setprio(0); \
    /* p8 */ BAR(); STGB(1, g3, 1); \
    WAITDS(); __builtin_amdgcn_s_setprio(1); MFMAQ(4, 0); \
    __builtin_amdgcn_s_setprio(0); VM6();

// register->global epilogue; zeroes acc for next tile
template<int EPI>
__device__ __forceinline__ void gemm_epilogue(
    floatx4 (&acc)[8][4], const float (&bv)[4],
    int mBase, int nBase, int wm, int wn, int lr, int quad,
    ushort* __restrict__ q_out, ushort* __restrict__ kT_out,
    ushort* __restrict__ vT_out, float* __restrict__ f_out)
{
    if (EPI == 0) {
        const float inv_scale = 0.35355339059327373f;  // 1/64^0.25
        const int seg = nBase >> 10;                   // 0=q, 1=k, 2=v
        if (seg == 0) {
            // q' = fm(q)/(z+1e-6); wave wn owns one full head's 64 columns,
            // z = 4-frag sum + shfl_xor over lr.
            #pragma unroll
            for (int mf = 0; mf < 8; mf++)
                #pragma unroll
                for (int i = 0; i < 4; i++) {
                    float f0 = feature_map((acc[mf][0][i] + bv[0]) * inv_scale);
                    float f1 = feature_map((acc[mf][1][i] + bv[1]) * inv_scale);
                    float f2 = feature_map((acc[mf][2][i] + bv[2]) * inv_scale);
                    float f3 = feature_map((acc[mf][3][i] + bv[3]) * inv_scale);
                    float z = f0 + f1 + f2 + f3;
                    z += __shfl_xor(z, 1); z += __shfl_xor(z, 2);
                    z += __shfl_xor(z, 4); z += __shfl_xor(z, 8);
                    const float inv = 1.0f / (z + 1e-6f);
                    const int t = mBase + wm * 128 + mf * 16 + quad * 4 + i;
                    const int cbase = nBase + wn * 64 + lr;
                    q_out[(size_t)t * C_ + cbase]      = f2bf(f0 * inv);
                    q_out[(size_t)t * C_ + cbase + 16] = f2bf(f1 * inv);
                    q_out[(size_t)t * C_ + cbase + 32] = f2bf(f2 * inv);
                    q_out[(size_t)t * C_ + cbase + 48] = f2bf(f3 * inv);
                }
        } else {
            ushort* dstT = (seg == 1) ? kT_out : vT_out;
            #pragma unroll
            for (int nf = 0; nf < 4; nf++) {
                const int c = (nBase + wn * 64 + nf * 16 + lr) & 1023;
                #pragma unroll
                for (int mf = 0; mf < 8; mf++) {
                    float v0 = acc[mf][nf][0] + bv[nf], v1 = acc[mf][nf][1] + bv[nf];
                    float v2 = acc[mf][nf][2] + bv[nf], v3 = acc[mf][nf][3] + bv[nf];
                    if (seg == 1) {
                        v0 = feature_map(v0 * inv_scale); v1 = feature_map(v1 * inv_scale);
                        v2 = feature_map(v2 * inv_scale); v3 = feature_map(v3 * inv_scale);
                    }
                    const int tt = mBase + wm * 128 + mf * 16 + quad * 4;
                    *(ushort4*)&dstT[(size_t)c * BT_ + tt] =
                        make_ushort4(f2bf(v0), f2bf(v1), f2bf(v2), f2bf(v3));
                }
            }
        }
    } else {
        #pragma unroll
        for (int nf = 0; nf < 4; nf++) {
            const int c = nBase + wn * 64 + nf * 16 + lr;
            #pragma unroll
            for (int mf = 0; mf < 8; mf++)
                #pragma unroll
                for (int i = 0; i < 4; i++) {
                    const int row = mBase + wm * 128 + mf * 16 + quad * 4 + i;
                    f_out[(size_t)row * C_ + c] = acc[mf][nf][i] + bv[nf];
                }
        }
    }
    #pragma unroll
    for (int i = 0; i < 8; i++)
        #pragma unroll
        for (int j = 0; j < 4; j++) acc[i][j] = (floatx4)0.0f;
}

template<int EPI, int NBX, int NTILE>
__device__ __forceinline__ void gemm_body(
    const ushort* __restrict__ A, const ushort* __restrict__ Bm,
    const float* __restrict__ bias,
    ushort* __restrict__ q_out, ushort* __restrict__ kT_out,
    ushort* __restrict__ vT_out, float* __restrict__ f_out)
{
    __shared__ __align__(16) unsigned char smem[131072];

    const int tid = threadIdx.x;
    const int wv = tid >> 6, l = tid & 63;
    const int wm = wv >> 2, wn = wv & 3;
    const int lr = l & 15, quad = l >> 4;

    int mB0, mB1, mB2, nB0, nB1, nB2;
    {
        const int tot = (int)gridDim.x * NTILE, cpx = tot >> 3;
        int lg0 = blockIdx.x;
        int w0 = (lg0 & 7) * cpx + (lg0 >> 3);
        mB0 = (w0 / NBX) * 256; nB0 = (w0 % NBX) * 256;
        if (NTILE > 1) {
            int lg1 = blockIdx.x + (int)gridDim.x;
            int w1 = (lg1 & 7) * cpx + (lg1 >> 3);
            mB1 = (w1 / NBX) * 256; nB1 = (w1 % NBX) * 256;
            int lg2 = blockIdx.x + 2 * (int)gridDim.x;
            int w2 = (lg2 & 7) * cpx + (lg2 >> 3);
            mB2 = (w2 / NBX) * 256; nB2 = (w2 % NBX) * 256;
        } else { mB1 = mB0; nB1 = nB0; mB2 = mB0; nB2 = nB0; }
    }
    // EPI=1: B panel differs per batch b = mBase>>12 (KWT[b])
    const size_t bOffB = (EPI == 1) ? (size_t)(mB0 >> 12) * ((size_t)C_ * C_) : 0;
    const char* Ab0 = (const char*)(A + (size_t)mB0 * C_);
    const char* Ab1 = (const char*)(A + (size_t)mB1 * C_);
    const char* Ab2 = (const char*)(A + (size_t)mB2 * C_);
    const char* Bb0 = (const char*)(Bm + bOffB + (size_t)nB0 * C_);
    const char* Bb1 = (const char*)(Bm + bOffB + (size_t)nB1 * C_);
    const char* Bb2 = (const char*)(Bm + bOffB + (size_t)nB2 * C_);

    float bv0[4], bv1[4], bv2[4];
    #pragma unroll
    for (int nf = 0; nf < 4; nf++) {
        bv0[nf] = bias[nB0 + wn * 64 + nf * 16 + lr];
        bv1[nf] = (NTILE > 1) ? bias[nB1 + wn * 64 + nf * 16 + lr] : bv0[nf];
        bv2[nf] = (NTILE > 1) ? bias[nB2 + wn * 64 + nf * 16 + lr] : bv0[nf];
    }

    const int s0 = tid >> 3;
    const int cb = ((tid & 7) * 16) ^ ((s0 & 7) << 4);
    const int aOf00 = (s0)       * 2048 + cb;
    const int aOf01 = (128 + s0) * 2048 + cb;
    const int aOf10 = (64 + s0)  * 2048 + cb;
    const int aOf11 = (192 + s0) * 2048 + cb;
    const int bq    = (s0 >> 5) * 64 + (s0 & 31);
    const int bOf00 = (bq)       * 2048 + cb;
    const int bOf01 = (bq + 128) * 2048 + cb;
    const int bOf10 = (bq + 32)  * 2048 + cb;
    const int bOf11 = (bq + 160) * 2048 + cb;

    const int aRowB = (wm * 64 + lr) * 128;
    const int bRowB = (wn * 32 + lr) * 128;
    const int cks0 = (quad * 16) ^ ((lr & 7) << 4);
    const int cks1 = 64 ^ cks0;

    floatx4 acc[8][4];
    #pragma unroll
    for (int i = 0; i < 8; i++)
        #pragma unroll
        for (int j = 0; j < 4; j++) acc[i][j] = (floatx4)0.0f;
    short8 aR[4][2], bR[4][2];

    STGA(0, 0, 0); STGB(0, 0, 0); STGB(1, 0, 0); STGA(1, 0, 0);
    STGA(0, 1, 1); STGB(0, 1, 1); STGB(1, 1, 1);
    asm volatile("s_waitcnt vmcnt(6)" ::: "memory");
    __builtin_amdgcn_sched_barrier(0);

    #pragma unroll 1
    for (int it = 0; it < 8; ++it) { ITERBODY(0) }
    gemm_epilogue<EPI>(acc, bv0, mB0, nB0, wm, wn, lr, quad,
                       q_out, kT_out, vT_out, f_out);
    if (NTILE > 1) {
        #pragma unroll 1
        for (int it = 0; it < 8; ++it) { ITERBODY(16) }
        gemm_epilogue<EPI>(acc, bv1, mB1, nB1, wm, wn, lr, quad,
                           q_out, kT_out, vT_out, f_out);
        #pragma unroll 1
        for (int it = 0; it < 8; ++it) { ITERBODY(32) }
        gemm_epilogue<EPI>(acc, bv2, mB2, nB2, wm, wn, lr, quad,
                           q_out, kT_out, vT_out, f_out);
    }
    asm volatile("s_waitcnt vmcnt(0)" ::: "memory");
}

__global__ __launch_bounds__(512, 2)
void qkv8_kernel(const ushort* __restrict__ A, const ushort* __restrict__ Bm,
                 const float* __restrict__ bias, ushort* __restrict__ q_out,
                 ushort* __restrict__ kT_out, ushort* __restrict__ vT_out)
{
    gemm_body<0, 12, 3>(A, Bm, bias, q_out, kT_out, vT_out, nullptr);
}

__global__ __launch_bounds__(512, 2)
void outproj8_kernel(const ushort* __restrict__ A, const ushort* __restrict__ Bm,
                     const float* __restrict__ bias, float* __restrict__ f_out)
{
    gemm_body<1, 4, 1>(A, Bm, bias, nullptr, nullptr, nullptr, f_out);
}

// ---------------------------------------------------------------------------
// K2: kv partials (NO atomics, no memset): kv_part[split][bh][d*64+m] =
//     sum over this split's 512 t of km[t][d]*v[t][m]. grid (8, 64).
// ---------------------------------------------------------------------------
__global__ __launch_bounds__(256)
void kv_accum_kernel(const ushort* __restrict__ kmT, const ushort* __restrict__ vT,
                     float* __restrict__ kv_part)
{
    const int tid = threadIdx.x;
    const int w = tid >> 6, l = tid & 63;
    const int wm = w >> 1, wn = w & 1;
    const int lr = l & 15, quad = l >> 4;
    const int bh = blockIdx.y;
    const int b = bh >> 4, h = bh & 15;
    const size_t t0 = (size_t)b * T_ + (size_t)blockIdx.x * 512;

    const ushort* Ar = kmT + (size_t)(h * 64 + wm * 32 + lr) * BT_ + t0 + quad * 8;
    const ushort* Br = vT  + (size_t)(h * 64 + wn * 32 + lr) * BT_ + t0 + quad * 8;

    floatx4 acc[2][2];
    #pragma unroll
    for (int i = 0; i < 2; i++)
        #pragma unroll
        for (int j = 0; j < 2; j++) acc[i][j] = (floatx4)0.0f;

    #pragma unroll 8
    for (int tt = 0; tt < 512; tt += 32) {
        const short8 af0 = *(const short8*)&Ar[tt];
        const short8 af1 = *(const short8*)&Ar[(size_t)16 * BT_ + tt];
        const short8 bf0 = *(const short8*)&Br[tt];
        const short8 bf1 = *(const short8*)&Br[(size_t)16 * BT_ + tt];
        acc[0][0] = __builtin_amdgcn_mfma_f32_16x16x32_bf16(af0, bf0, acc[0][0], 0, 0, 0);
        acc[0][1] = __builtin_amdgcn_mfma_f32_16x16x32_bf16(af0, bf1, acc[0][1], 0, 0, 0);
        acc[1][0] = __builtin_amdgcn_mfma_f32_16x16x32_bf16(af1, bf0, acc[1][0], 0, 0, 0);
        acc[1][1] = __builtin_amdgcn_mfma_f32_16x16x32_bf16(af1, bf1, acc[1][1], 0, 0, 0);
    }

    float* kvb = kv_part + ((size_t)blockIdx.x * 64 + bh) * (D_ * D_);
    #pragma unroll
    for (int i = 0; i < 2; i++)
        #pragma unroll
        for (int j = 0; j < 2; j++)
            #pragma unroll
            for (int r = 0; r < 4; r++) {
                const int d = wm * 32 + i * 16 + quad * 4 + r;
                const int m = wn * 32 + j * 16 + lr;
                kvb[d * 64 + m] = acc[i][j][r];
            }
}

// ---------------------------------------------------------------------------
// K3: KWT[b][c][h*64+d] = sum_m (sum_s kv_part[s][bh][d][m]) * Wout[h*64+m][c]
//     grid (4 cblk, 64 bh); wave w: c-range cblk*256 + w*64; K=64.
// ---------------------------------------------------------------------------
__global__ __launch_bounds__(256)
void kw_kernel(const float* __restrict__ kv_part, const ushort* __restrict__ WoutT,
               ushort* __restrict__ KWT)
{
    const int tid = threadIdx.x;
    const int w = tid >> 6, l = tid & 63;
    const int lr = l & 15, quad = l >> 4;
    const int bh = blockIdx.y, b = bh >> 4, h = bh & 15;
    const int c0 = blockIdx.x * 256 + w * 64;

    short8 bf[4][2];
    #pragma unroll
    for (int df = 0; df < 4; df++)
        #pragma unroll
        for (int ks = 0; ks < 2; ks++) {
            const int off = (df * 16 + lr) * 64 + ks * 32 + quad * 8;
            float4 u0 = make_float4(0.f, 0.f, 0.f, 0.f);
            float4 u1 = make_float4(0.f, 0.f, 0.f, 0.f);
            #pragma unroll
            for (int s = 0; s < 8; s++) {
                const float* src = kv_part + ((size_t)s * 64 + bh) * (D_ * D_) + off;
                const float4 a0 = *(const float4*)src;
                const float4 a1 = *(const float4*)(src + 4);
                u0.x += a0.x; u0.y += a0.y; u0.z += a0.z; u0.w += a0.w;
                u1.x += a1.x; u1.y += a1.y; u1.z += a1.z; u1.w += a1.w;
            }
            short8 t;
            t[0] = (short)f2bf(u0.x); t[1] = (short)f2bf(u0.y);
            t[2] = (short)f2bf(u0.z); t[3] = (short)f2bf(u0.w);
            t[4] = (short)f2bf(u1.x); t[5] = (short)f2bf(u1.y);
            t[6] = (short)f2bf(u1.z); t[7] = (short)f2bf(u1.w);
            bf[df][ks] = t;
        }

    floatx4 acc[4][4];
    #pragma unroll
    for (int i = 0; i < 4; i++)
        #pragma unroll
        for (int j = 0; j < 4; j++) acc[i][j] = (floatx4)0.0f;

    #pragma unroll
    for (int ks = 0; ks < 2; ks++) {
        short8 af[4];
        #pragma unroll
        for (int cf = 0; cf < 4; cf++)
            af[cf] = *(const short8*)&WoutT[(size_t)(c0 + cf * 16 + lr) * C_
                                            + h * 64 + ks * 32 + quad * 8];
        #pragma unroll
        for (int cf = 0; cf < 4; cf++)
            #pragma unroll
            for (int df = 0; df < 4; df++)
                acc[cf][df] = __builtin_amdgcn_mfma_f32_16x16x32_bf16(
                    af[cf], bf[df][ks], acc[cf][df], 0, 0, 0);
    }

    ushort* dst = KWT + (size_t)b * (C_ * C_);
    #pragma unroll
    for (int cf = 0; cf < 4; cf++)
        #pragma unroll
        for (int i = 0; i < 4; i++) {
            const int c = c0 + cf * 16 + quad * 4 + i;
            #pragma unroll
            for (int df = 0; df < 4; df++)
                dst[(size_t)c * C_ + h * 64 + df * 16 + lr] = f2bf(acc[cf][df][i]);
        }
}

// ---------------------------------------------------------------------------
// Workspace map:
//   ws:    xb 33.5M (-> KWT 8M + kv_part 8M after QKV) | WqkvT 6.3M |
//          WoutT 2M | qs 33.5M | (1M spare)             (= 76,546,048 B)
//   d_out: kmT 33.5M | vT 33.5M  (both dead before outproj writes out)
// ---------------------------------------------------------------------------
extern "C" void kernel_launch(void* const* d_in, const int* in_sizes, int n_in,
                              void* d_out, int out_size, void* d_ws, size_t ws_size,
                              hipStream_t stream)
{
    const float* x    = (const float*)d_in[0];
    const float* Wqkv = (const float*)d_in[1];
    const float* bqkv = (const float*)d_in[2];
    const float* Wout = (const float*)d_in[3];
    const float* bout = (const float*)d_in[4];
    float* out = (float*)d_out;

    char* ws = (char*)d_ws;
    ushort* xb      = (ushort*)ws;                      // 33,554,432 B
    ushort* WqkvT   = (ushort*)(ws + 33554432);         //  6,291,456 B
    ushort* WoutT   = (ushort*)(ws + 39845888);         //  2,097,152 B
    ushort* qs      = (ushort*)(ws + 41943040);         // 33,554,432 B (q')
    ushort* KWT     = (ushort*)ws;                      // alias xb+0 (8 MB)
    float*  kv_part = (float*)(ws + 8388608);           // alias xb+8M (8 MB)
    ushort* kmT     = (ushort*)d_out;                   // scratch in d_out
    ushort* vT      = (ushort*)((char*)d_out + 33554432);

    prep_kernel<<<6144, 256, 0, stream>>>((const float4*)x, xb,
                                          Wqkv, WqkvT, Wout, WoutT);

    qkv8_kernel<<<dim3(256), 512, 0, stream>>>(xb, WqkvT, bqkv, qs, kmT, vT);
    kv_accum_kernel<<<dim3(8, B_ * H_), 256, 0, stream>>>(kmT, vT, kv_part);
    kw_kernel<<<dim3(4, B_ * H_), 256, 0, stream>>>(kv_part, WoutT, KWT);
    outproj8_kernel<<<dim3(256), 512, 0, stream>>>(qs, KWT, bout, out);
}